// Round 1
// baseline (749.182 us; speedup 1.0000x reference)
//
#include <hip/hip_runtime.h>
#include <math.h>

#define NH 8
#define NP 4
#define DD 64
#define DM 512

// ---------------------------------------------------------------------------
// C[M,N] = A[M,K] @ W[N,K]^T + bias[N]      (all fp32, row-major)
// Tile 128x128x16, 256 threads, 8x8 micro-tile per thread.
// ---------------------------------------------------------------------------
__global__ __launch_bounds__(256) void gemm_nt_f32(
    const float* __restrict__ A, const float* __restrict__ W,
    const float* __restrict__ bias, float* __restrict__ C,
    int M, int N, int K)
{
    constexpr int BM = 128, BN = 128, BK = 16;
    __shared__ float As[BK][BM + 4];   // +4 keeps rows 16B-aligned for b128 reads
    __shared__ float Bs[BK][BN + 4];
    const int tid = threadIdx.x;
    const int m0 = blockIdx.x * BM;
    const int n0 = blockIdx.y * BN;
    const int tx = tid & 15;       // col group
    const int ty = tid >> 4;       // row group

    float acc[8][8];
#pragma unroll
    for (int i = 0; i < 8; ++i)
#pragma unroll
        for (int j = 0; j < 8; ++j) acc[i][j] = 0.f;

    for (int k0 = 0; k0 < K; k0 += BK) {
        // stage A and W tiles (transposed into LDS: [k][row])
#pragma unroll
        for (int i = 0; i < 2; ++i) {
            int f = tid * 2 + i;            // 0..511
            int r = f >> 2;                 // 0..127
            int c = (f & 3) << 2;           // 0,4,8,12
            float4 a4 = *(const float4*)&A[(size_t)(m0 + r) * K + k0 + c];
            As[c + 0][r] = a4.x; As[c + 1][r] = a4.y;
            As[c + 2][r] = a4.z; As[c + 3][r] = a4.w;
            int wr = n0 + r;
            float4 b4 = make_float4(0.f, 0.f, 0.f, 0.f);
            if (wr < N) b4 = *(const float4*)&W[(size_t)wr * K + k0 + c];
            Bs[c + 0][r] = b4.x; Bs[c + 1][r] = b4.y;
            Bs[c + 2][r] = b4.z; Bs[c + 3][r] = b4.w;
        }
        __syncthreads();
#pragma unroll
        for (int kk = 0; kk < BK; ++kk) {
            float4 a0 = *(const float4*)&As[kk][ty * 8 + 0];
            float4 a1 = *(const float4*)&As[kk][ty * 8 + 4];
            float4 b0 = *(const float4*)&Bs[kk][tx * 8 + 0];
            float4 b1 = *(const float4*)&Bs[kk][tx * 8 + 4];
            float av[8] = {a0.x, a0.y, a0.z, a0.w, a1.x, a1.y, a1.z, a1.w};
            float bv[8] = {b0.x, b0.y, b0.z, b0.w, b1.x, b1.y, b1.z, b1.w};
#pragma unroll
            for (int i = 0; i < 8; ++i)
#pragma unroll
                for (int j = 0; j < 8; ++j)
                    acc[i][j] = fmaf(av[i], bv[j], acc[i][j]);
        }
        __syncthreads();
    }

    // epilogue: add bias, store
#pragma unroll
    for (int i = 0; i < 8; ++i) {
        int m = m0 + ty * 8 + i;
        float* crow = C + (size_t)m * N;
        int n = n0 + tx * 8;
        if (n + 7 < N) {
            float4 o0 = make_float4(acc[i][0] + bias[n + 0], acc[i][1] + bias[n + 1],
                                    acc[i][2] + bias[n + 2], acc[i][3] + bias[n + 3]);
            float4 o1 = make_float4(acc[i][4] + bias[n + 4], acc[i][5] + bias[n + 5],
                                    acc[i][6] + bias[n + 6], acc[i][7] + bias[n + 7]);
            *(float4*)&crow[n + 0] = o0;
            *(float4*)&crow[n + 4] = o1;
        } else {
#pragma unroll
            for (int j = 0; j < 8; ++j)
                if (n + j < N) crow[n + j] = acc[i][j] + bias[n + j];
        }
    }
}

// ---------------------------------------------------------------------------
// Deformable attention core. One wave (64 lanes) per (b,l,h); lane = d.
// q,k,v: (B,L,DM) row-major (head h occupies cols h*64..h*64+63)
// off,logit: (B,L,NH,NP).  out: (B,L,DM).  out may alias q (each wave only
// overwrites the q row it alone consumes, after the data dependency).
// ---------------------------------------------------------------------------
__global__ __launch_bounds__(256) void deform_attn_f32(
    const float* q, const float* __restrict__ k, const float* __restrict__ v,
    const float* __restrict__ off, const float* __restrict__ logit,
    float* out, int B, int L)
{
    const int wave = threadIdx.x >> 6;
    const int lane = threadIdx.x & 63;
    const long long gw = (long long)blockIdx.x * 4 + wave;  // over B*L*NH
    const int h = (int)(gw % NH);
    const long long bl = gw / NH;                            // b*L + l
    const int l = (int)(bl % L);
    const int b = (int)(bl / L);

    const size_t rowbase = (size_t)bl * DM + (size_t)h * DD;
    const float qd = q[rowbase + lane];

    const size_t obase = (size_t)bl * (NH * NP) + (size_t)h * NP;

    float t[NP], vs[NP];
#pragma unroll
    for (int p = 0; p < NP; ++p) {
        float pos = (float)l + off[obase + p];
        pos = fminf(fmaxf(pos, 0.f), (float)(L - 1));
        float f = floorf(pos);
        int i0 = (int)f;
        int i1 = min(i0 + 1, L - 1);
        float w = pos - f;
        const size_t r0 = ((size_t)b * L + i0) * DM + (size_t)h * DD;
        const size_t r1 = ((size_t)b * L + i1) * DM + (size_t)h * DD;
        float ks = (1.f - w) * k[r0 + lane] + w * k[r1 + lane];
        vs[p]    = (1.f - w) * v[r0 + lane] + w * v[r1 + lane];
        float d = qd * ks;
#pragma unroll
        for (int m = 32; m >= 1; m >>= 1) d += __shfl_xor(d, m);
        t[p] = d * 0.125f + logit[obase + p];   // 1/sqrt(64) = 0.125
    }

    // softmax over P=4 (replicated across lanes)
    float mx = fmaxf(fmaxf(t[0], t[1]), fmaxf(t[2], t[3]));
    float e0 = __expf(t[0] - mx), e1 = __expf(t[1] - mx);
    float e2 = __expf(t[2] - mx), e3 = __expf(t[3] - mx);
    float inv = 1.f / (e0 + e1 + e2 + e3);
    float o = (e0 * vs[0] + e1 * vs[1] + e2 * vs[2] + e3 * vs[3]) * inv;

    out[rowbase + lane] = o;
}

// ---------------------------------------------------------------------------
extern "C" void kernel_launch(void* const* d_in, const int* in_sizes, int n_in,
                              void* d_out, int out_size, void* d_ws, size_t ws_size,
                              hipStream_t stream) {
    const float* q_in  = (const float*)d_in[0];
    const float* kv_in = (const float*)d_in[1];
    const float* Wq = (const float*)d_in[2];  const float* bq = (const float*)d_in[3];
    const float* Wk = (const float*)d_in[4];  const float* bk = (const float*)d_in[5];
    const float* Wv = (const float*)d_in[6];  const float* bv = (const float*)d_in[7];
    const float* Wo_= (const float*)d_in[8];  const float* bo_= (const float*)d_in[9];   // Woff/boff
    const float* Wa = (const float*)d_in[10]; const float* ba = (const float*)d_in[11];
    const float* Wo = (const float*)d_in[12]; const float* bo = (const float*)d_in[13];

    const int M = in_sizes[0] / DM;      // B*L = 16384
    const int L = 4096;
    const int B = M / L;

    float* ws = (float*)d_ws;
    float* q_ws   = ws;                          // (M, DM) — later overwritten by attn out
    float* k_ws   = q_ws + (size_t)M * DM;
    float* v_ws   = k_ws + (size_t)M * DM;
    float* off_ws = v_ws + (size_t)M * DM;       // (M, 32)
    float* log_ws = off_ws + (size_t)M * (NH * NP);

    dim3 blk(256);
    dim3 g512(M / 128, DM / 128);
    dim3 g32(M / 128, 1);

    hipLaunchKernelGGL(gemm_nt_f32, g512, blk, 0, stream, q_in,  Wq, bq, q_ws, M, DM, DM);
    hipLaunchKernelGGL(gemm_nt_f32, g512, blk, 0, stream, kv_in, Wk, bk, k_ws, M, DM, DM);
    hipLaunchKernelGGL(gemm_nt_f32, g512, blk, 0, stream, kv_in, Wv, bv, v_ws, M, DM, DM);
    hipLaunchKernelGGL(gemm_nt_f32, g32,  blk, 0, stream, q_in,  Wo_, bo_, off_ws, M, NH * NP, DM);
    hipLaunchKernelGGL(gemm_nt_f32, g32,  blk, 0, stream, q_in,  Wa,  ba,  log_ws, M, NH * NP, DM);

    // attention: one wave per (b,l,h); out aliases q_ws (safe: per-wave RAW dep)
    int nwaves = M * NH;
    hipLaunchKernelGGL(deform_attn_f32, dim3(nwaves / 4), blk, 0, stream,
                       q_ws, k_ws, v_ws, off_ws, log_ws, q_ws, B, L);

    hipLaunchKernelGGL(gemm_nt_f32, g512, blk, 0, stream, q_ws, Wo, bo, (float*)d_out, M, DM, DM);
}

// Round 2
// 266.320 us; speedup vs baseline: 2.8131x; 2.8131x over previous
//
#include <hip/hip_runtime.h>
#include <math.h>

#define NH 8
#define NP 4
#define DD 64
#define DM 512

typedef unsigned short u16;
typedef unsigned int u32;

using frag_ab = __attribute__((ext_vector_type(8))) short;  // 8 bf16 (4 VGPRs)
using f32x4   = __attribute__((ext_vector_type(4))) float;  // 4 fp32 acc

__device__ __forceinline__ u16 f2b(float f) {               // fp32 -> bf16 (RNE)
    u32 u = __float_as_uint(f);
    u32 r = (u + 0x7FFFu + ((u >> 16) & 1u)) >> 16;
    return (u16)r;
}
__device__ __forceinline__ float b2f(u16 b) {
    return __uint_as_float(((u32)b) << 16);
}

#define GLOBAL_AS __attribute__((address_space(1)))
#define LDS_AS    __attribute__((address_space(3)))
__device__ __forceinline__ void async_copy16(void* lds, const void* g) {
    // per-lane global src; LDS dest = wave-uniform base + lane*16
    __builtin_amdgcn_global_load_lds((const GLOBAL_AS u32*)g, (LDS_AS u32*)lds, 16, 0, 0);
}

// ---------------------------------------------------------------------------
// C[M,N] = A[M,K](bf16) @ Wt[N,K](bf16)^T + bias[N](f32)
// BM=128, BK=32, BN in {128,64}. 256 threads (4 waves), 16x16x32 bf16 MFMA.
// Wave tile: BN=128 -> 64x64 (4x4 frags); BN=64 -> 32x64 (2x4 frags).
// ---------------------------------------------------------------------------
template <int BN, bool OUT_BF16>
__global__ __launch_bounds__(256) void gemm_bt_bf16(
    const u16* __restrict__ A, const u16* __restrict__ Wt,
    const float* __restrict__ bias, void* __restrict__ C,
    int M, int N, int K)
{
    constexpr int BM = 128, BK = 32;
    __shared__ u16 sA[BM * BK];   // row-major [row][32]
    __shared__ u16 sB[BN * BK];

    const int tid  = threadIdx.x;
    const int wave = tid >> 6;
    const int lane = tid & 63;
    const int m0 = blockIdx.x * BM;
    const int n0 = blockIdx.y * BN;

    constexpr int WR = (BN == 128) ? 4 : 2;   // 16-row frags per wave
    constexpr int WC = 4;                     // 16-col frags per wave
    const int wrow = (BN == 128) ? 64 * (wave >> 1) : 32 * wave;
    const int wcol = (BN == 128) ? 64 * (wave & 1) : 0;

    f32x4 acc[WR][WC] = {};

    const int lr = lane & 15;     // frag row (A) / col (B,W-row)
    const int kg = lane >> 4;     // k-group: elements kg*8..kg*8+7

    const int kiters = K >> 5;
    for (int kt = 0; kt < kiters; ++kt) {
        const int k0 = kt << 5;
        // ---- stage A tile: 8 KB = 8 wave-groups x 1 KB ----
#pragma unroll
        for (int i = 0; i < 2; ++i) {
            int grp = i * 4 + wave;                 // 0..7 (uniform per wave)
            int c   = grp * 64 + lane;              // 16B chunk id 0..511
            const u16* g = A + (size_t)(m0 + (c >> 2)) * K + k0 + ((c & 3) << 3);
            async_copy16(&sA[grp * 512], g);
        }
        // ---- stage B tile: BN*64 bytes ----
#pragma unroll
        for (int i = 0; i < BN / 64; ++i) {
            int grp = i * 4 + wave;
            int c   = grp * 64 + lane;
            const u16* g = Wt + (size_t)(n0 + (c >> 2)) * K + k0 + ((c & 3) << 3);
            async_copy16(&sB[grp * 512], g);
        }
        __syncthreads();   // drains vmcnt (global_load_lds) + barrier

        frag_ab af[WR], bfr[WC];
#pragma unroll
        for (int i = 0; i < WR; ++i)
            af[i] = *(const frag_ab*)&sA[(wrow + i * 16 + lr) * 32 + kg * 8];
#pragma unroll
        for (int j = 0; j < WC; ++j)
            bfr[j] = *(const frag_ab*)&sB[(wcol + j * 16 + lr) * 32 + kg * 8];
#pragma unroll
        for (int i = 0; i < WR; ++i)
#pragma unroll
            for (int j = 0; j < WC; ++j)
                acc[i][j] = __builtin_amdgcn_mfma_f32_16x16x32_bf16(
                    af[i], bfr[j], acc[i][j], 0, 0, 0);
        __syncthreads();
    }

    // epilogue: D mapping col=lane&15, row=(lane>>4)*4+reg
    const int crow0 = (lane >> 4) * 4;
#pragma unroll
    for (int i = 0; i < WR; ++i) {
#pragma unroll
        for (int j = 0; j < WC; ++j) {
            int col = n0 + wcol + j * 16 + (lane & 15);
            float bv = bias[col];
#pragma unroll
            for (int r = 0; r < 4; ++r) {
                int row = m0 + wrow + i * 16 + crow0 + r;
                float val = acc[i][j][r] + bv;
                if (OUT_BF16)
                    ((u16*)C)[(size_t)row * N + col] = f2b(val);
                else
                    ((float*)C)[(size_t)row * N + col] = val;
            }
        }
    }
}

// ---------------------------------------------------------------------------
// casts
// ---------------------------------------------------------------------------
__global__ __launch_bounds__(256) void cast_f32_to_bf16(
    const float* __restrict__ in, u16* __restrict__ out, int n4)
{
    int i = blockIdx.x * 256 + threadIdx.x;
    if (i >= n4) return;
    float4 v = ((const float4*)in)[i];
    ushort4 o;
    o.x = f2b(v.x); o.y = f2b(v.y); o.z = f2b(v.z); o.w = f2b(v.w);
    ((ushort4*)out)[i] = o;
}

// four 512x512 weights in one launch; per4 = 512*512/4
__global__ __launch_bounds__(256) void cast_weights4(
    const float* w0, const float* w1, const float* w2, const float* w3,
    u16* o0, u16* o1, u16* o2, u16* o3, int per4)
{
    int tid = blockIdx.x * 256 + threadIdx.x;
    int seg = tid / per4, off = tid - seg * per4;
    const float* w = (seg == 0) ? w0 : (seg == 1) ? w1 : (seg == 2) ? w2 : w3;
    u16* o = (seg == 0) ? o0 : (seg == 1) ? o1 : (seg == 2) ? o2 : o3;
    float4 v = ((const float4*)w)[off];
    ushort4 t;
    t.x = f2b(v.x); t.y = f2b(v.y); t.z = f2b(v.z); t.w = f2b(v.w);
    ((ushort4*)o)[off] = t;
}

// pack [Woff;Wa] -> (64,512) bf16 and [boff;ba] -> (64,) f32
__global__ __launch_bounds__(256) void pack_offa(
    const float* __restrict__ Woff, const float* __restrict__ Wa,
    const float* __restrict__ boff, const float* __restrict__ ba,
    u16* __restrict__ wc, float* __restrict__ bc, int n)  // n = 32*512
{
    int i = blockIdx.x * 256 + threadIdx.x;
    if (i < n) {
        wc[i]     = f2b(Woff[i]);
        wc[n + i] = f2b(Wa[i]);
    }
    if (i < 32) { bc[i] = boff[i]; bc[32 + i] = ba[i]; }
}

// ---------------------------------------------------------------------------
// attention core: one wave per (b,l,h), lane = d.  bf16 q/k/v, f32 off/logit.
// ---------------------------------------------------------------------------
__global__ __launch_bounds__(256) void deform_attn_bf16(
    const u16* __restrict__ q, const u16* __restrict__ k,
    const u16* __restrict__ v, const float* __restrict__ offlog,
    u16* __restrict__ out, int B, int L)
{
    const int wave = threadIdx.x >> 6;
    const int lane = threadIdx.x & 63;
    const long long gw = (long long)blockIdx.x * 4 + wave;   // over B*L*NH
    const int h = (int)(gw % NH);
    const long long bl = gw / NH;
    const int l = (int)(bl % L);
    const int b = (int)(bl / L);

    const size_t rowbase = (size_t)bl * DM + (size_t)h * DD;
    const float qd = b2f(q[rowbase + lane]);
    const size_t obase = (size_t)bl * 64 + (size_t)h * NP;

    float t[NP], vs[NP];
#pragma unroll
    for (int p = 0; p < NP; ++p) {
        float pos = (float)l + offlog[obase + p];
        pos = fminf(fmaxf(pos, 0.f), (float)(L - 1));
        float f = floorf(pos);
        int i0 = (int)f;
        int i1 = min(i0 + 1, L - 1);
        float w = pos - f;
        const size_t r0 = ((size_t)b * L + i0) * DM + (size_t)h * DD;
        const size_t r1 = ((size_t)b * L + i1) * DM + (size_t)h * DD;
        float ks = (1.f - w) * b2f(k[r0 + lane]) + w * b2f(k[r1 + lane]);
        vs[p]    = (1.f - w) * b2f(v[r0 + lane]) + w * b2f(v[r1 + lane]);
        float d = qd * ks;
#pragma unroll
        for (int m = 32; m >= 1; m >>= 1) d += __shfl_xor(d, m);
        t[p] = d * 0.125f + offlog[obase + 32 + p];
    }

    float mx = fmaxf(fmaxf(t[0], t[1]), fmaxf(t[2], t[3]));
    float e0 = __expf(t[0] - mx), e1 = __expf(t[1] - mx);
    float e2 = __expf(t[2] - mx), e3 = __expf(t[3] - mx);
    float inv = 1.f / (e0 + e1 + e2 + e3);
    float o = (e0 * vs[0] + e1 * vs[1] + e2 * vs[2] + e3 * vs[3]) * inv;

    out[rowbase + lane] = f2b(o);
}

// ---------------------------------------------------------------------------
extern "C" void kernel_launch(void* const* d_in, const int* in_sizes, int n_in,
                              void* d_out, int out_size, void* d_ws, size_t ws_size,
                              hipStream_t stream) {
    const float* q_in  = (const float*)d_in[0];
    const float* kv_in = (const float*)d_in[1];
    const float* Wq = (const float*)d_in[2];  const float* bq = (const float*)d_in[3];
    const float* Wk = (const float*)d_in[4];  const float* bk = (const float*)d_in[5];
    const float* Wv = (const float*)d_in[6];  const float* bv = (const float*)d_in[7];
    const float* Woff=(const float*)d_in[8];  const float* boff=(const float*)d_in[9];
    const float* Wa = (const float*)d_in[10]; const float* ba = (const float*)d_in[11];
    const float* Wo = (const float*)d_in[12]; const float* bo = (const float*)d_in[13];

    const int M = in_sizes[0] / DM;     // B*L = 16384
    const int L = 4096;
    const int B = M / L;

    // workspace carve-up (bytes)
    char* p = (char*)d_ws;
    u16* qb    = (u16*)p;                 p += (size_t)M * DM * 2;     // also attn_out later
    u16* kvb   = (u16*)p;                 p += (size_t)M * DM * 2;
    u16* Wqb   = (u16*)p;                 p += (size_t)DM * DM * 2;
    u16* Wkb   = (u16*)p;                 p += (size_t)DM * DM * 2;
    u16* Wvb   = (u16*)p;                 p += (size_t)DM * DM * 2;
    u16* Wob   = (u16*)p;                 p += (size_t)DM * DM * 2;
    u16* wcomb = (u16*)p;                 p += (size_t)64 * DM * 2;
    float* bc  = (float*)p;               p += 64 * 4;
    u16* q_ws  = (u16*)p;                 p += (size_t)M * DM * 2;
    u16* k_ws  = (u16*)p;                 p += (size_t)M * DM * 2;
    u16* v_ws  = (u16*)p;                 p += (size_t)M * DM * 2;
    float* offlog = (float*)p;            p += (size_t)M * 64 * 4;

    dim3 blk(256);

    // casts
    int n4 = (M * DM) / 4;
    hipLaunchKernelGGL(cast_f32_to_bf16, dim3((n4 + 255) / 256), blk, 0, stream, q_in,  qb,  n4);
    hipLaunchKernelGGL(cast_f32_to_bf16, dim3((n4 + 255) / 256), blk, 0, stream, kv_in, kvb, n4);
    int per4 = (DM * DM) / 4;
    hipLaunchKernelGGL(cast_weights4, dim3((4 * per4) / 256), blk, 0, stream,
                       Wq, Wk, Wv, Wo, Wqb, Wkb, Wvb, Wob, per4);
    hipLaunchKernelGGL(pack_offa, dim3((32 * DM + 255) / 256), blk, 0, stream,
                       Woff, Wa, boff, ba, wcomb, bc, 32 * DM);

    // projections (bf16 MFMA)
    dim3 g512(M / 128, DM / 128);
    hipLaunchKernelGGL((gemm_bt_bf16<128, true>), g512, blk, 0, stream, qb,  Wqb, bq, q_ws, M, DM, DM);
    hipLaunchKernelGGL((gemm_bt_bf16<128, true>), g512, blk, 0, stream, kvb, Wkb, bk, k_ws, M, DM, DM);
    hipLaunchKernelGGL((gemm_bt_bf16<128, true>), g512, blk, 0, stream, kvb, Wvb, bv, v_ws, M, DM, DM);
    hipLaunchKernelGGL((gemm_bt_bf16<64, false>), dim3(M / 128, 1), blk, 0, stream,
                       qb, wcomb, bc, offlog, M, 64, DM);

    // attention: one wave per (b,l,h); out -> qb (qb's last read was above)
    int nwaves = M * NH;
    hipLaunchKernelGGL(deform_attn_bf16, dim3(nwaves / 4), blk, 0, stream,
                       q_ws, k_ws, v_ws, offlog, qb, B, L);

    // output projection -> fp32 d_out
    hipLaunchKernelGGL((gemm_bt_bf16<128, false>), g512, blk, 0, stream,
                       qb, Wob, bo, (float*)d_out, M, DM, DM);
}

// Round 3
// 236.471 us; speedup vs baseline: 3.1682x; 1.1262x over previous
//
#include <hip/hip_runtime.h>
#include <math.h>

#define NH 8
#define NP 4
#define DD 64
#define DM 512

typedef unsigned short u16;
typedef unsigned int u32;

using frag_ab = __attribute__((ext_vector_type(8))) short;  // 8 bf16 (4 VGPRs)
using f32x4   = __attribute__((ext_vector_type(4))) float;  // 4 fp32 acc

__device__ __forceinline__ u16 f2b(float f) {               // fp32 -> bf16 (RNE)
    u32 u = __float_as_uint(f);
    u32 r = (u + 0x7FFFu + ((u >> 16) & 1u)) >> 16;
    return (u16)r;
}
__device__ __forceinline__ float b2f(u16 b) {
    return __uint_as_float(((u32)b) << 16);
}

#define GLOBAL_AS __attribute__((address_space(1)))
#define LDS_AS    __attribute__((address_space(3)))
__device__ __forceinline__ void async_copy16(void* lds, const void* g) {
    __builtin_amdgcn_global_load_lds((const GLOBAL_AS u32*)g, (LDS_AS u32*)lds, 16, 0, 0);
}

// ---------------------------------------------------------------------------
// C[M,N] = A[M,K](bf16) @ Wt[N,K](bf16)^T + bias[N](f32)
// ---------------------------------------------------------------------------
template <int BN, bool OUT_BF16>
__global__ __launch_bounds__(256) void gemm_bt_bf16(
    const u16* __restrict__ A, const u16* __restrict__ Wt,
    const float* __restrict__ bias, void* __restrict__ C,
    int M, int N, int K)
{
    constexpr int BM = 128, BK = 32;
    __shared__ u16 sA[BM * BK];
    __shared__ u16 sB[BN * BK];

    const int tid  = threadIdx.x;
    const int wave = tid >> 6;
    const int lane = tid & 63;
    const int m0 = blockIdx.x * BM;
    const int n0 = blockIdx.y * BN;

    constexpr int WR = (BN == 128) ? 4 : 2;
    constexpr int WC = 4;
    const int wrow = (BN == 128) ? 64 * (wave >> 1) : 32 * wave;
    const int wcol = (BN == 128) ? 64 * (wave & 1) : 0;

    f32x4 acc[WR][WC] = {};

    const int lr = lane & 15;
    const int kg = lane >> 4;

    const int kiters = K >> 5;
    for (int kt = 0; kt < kiters; ++kt) {
        const int k0 = kt << 5;
#pragma unroll
        for (int i = 0; i < 2; ++i) {
            int grp = i * 4 + wave;
            int c   = grp * 64 + lane;
            const u16* g = A + (size_t)(m0 + (c >> 2)) * K + k0 + ((c & 3) << 3);
            async_copy16(&sA[grp * 512], g);
        }
#pragma unroll
        for (int i = 0; i < BN / 64; ++i) {
            int grp = i * 4 + wave;
            int c   = grp * 64 + lane;
            const u16* g = Wt + (size_t)(n0 + (c >> 2)) * K + k0 + ((c & 3) << 3);
            async_copy16(&sB[grp * 512], g);
        }
        __syncthreads();

        frag_ab af[WR], bfr[WC];
#pragma unroll
        for (int i = 0; i < WR; ++i)
            af[i] = *(const frag_ab*)&sA[(wrow + i * 16 + lr) * 32 + kg * 8];
#pragma unroll
        for (int j = 0; j < WC; ++j)
            bfr[j] = *(const frag_ab*)&sB[(wcol + j * 16 + lr) * 32 + kg * 8];
#pragma unroll
        for (int i = 0; i < WR; ++i)
#pragma unroll
            for (int j = 0; j < WC; ++j)
                acc[i][j] = __builtin_amdgcn_mfma_f32_16x16x32_bf16(
                    af[i], bfr[j], acc[i][j], 0, 0, 0);
        __syncthreads();
    }

    const int crow0 = (lane >> 4) * 4;
#pragma unroll
    for (int i = 0; i < WR; ++i) {
#pragma unroll
        for (int j = 0; j < WC; ++j) {
            int col = n0 + wcol + j * 16 + (lane & 15);
            float bv = bias[col];
#pragma unroll
            for (int r = 0; r < 4; ++r) {
                int row = m0 + wrow + i * 16 + crow0 + r;
                float val = acc[i][j][r] + bv;
                if (OUT_BF16)
                    ((u16*)C)[(size_t)row * N + col] = f2b(val);
                else
                    ((float*)C)[(size_t)row * N + col] = val;
            }
        }
    }
}

// ---------------------------------------------------------------------------
// casts / packs
// ---------------------------------------------------------------------------
__global__ __launch_bounds__(256) void cast_f32_to_bf16(
    const float* __restrict__ in, u16* __restrict__ out, int n4)
{
    int i = blockIdx.x * 256 + threadIdx.x;
    if (i >= n4) return;
    float4 v = ((const float4*)in)[i];
    ushort4 o;
    o.x = f2b(v.x); o.y = f2b(v.y); o.z = f2b(v.z); o.w = f2b(v.w);
    ((ushort4*)out)[i] = o;
}

__global__ __launch_bounds__(256) void cast_weights4(
    const float* w0, const float* w1, const float* w2, const float* w3,
    u16* o0, u16* o1, u16* o2, u16* o3, int per4)
{
    int tid = blockIdx.x * 256 + threadIdx.x;
    int seg = tid / per4, off = tid - seg * per4;
    const float* w = (seg == 0) ? w0 : (seg == 1) ? w1 : (seg == 2) ? w2 : w3;
    u16* o = (seg == 0) ? o0 : (seg == 1) ? o1 : (seg == 2) ? o2 : o3;
    float4 v = ((const float4*)w)[off];
    ushort4 t;
    t.x = f2b(v.x); t.y = f2b(v.y); t.z = f2b(v.z); t.w = f2b(v.w);
    ((ushort4*)o)[off] = t;
}

__global__ __launch_bounds__(256) void pack_offa(
    const float* __restrict__ Woff, const float* __restrict__ Wa,
    const float* __restrict__ boff, const float* __restrict__ ba,
    u16* __restrict__ wc, float* __restrict__ bc, int n)
{
    int i = blockIdx.x * 256 + threadIdx.x;
    if (i < n) {
        wc[i]     = f2b(Woff[i]);
        wc[n + i] = f2b(Wa[i]);
    }
    if (i < 32) { bc[i] = boff[i]; bc[32 + i] = ba[i]; }
}

// ---------------------------------------------------------------------------
// Banded deformable attention. One wave per (b, h, 16-query block).
// Band = k/v rows [l0-8, l0+24).  S = q @ k_band^T via MFMA (4), softmax+lerp
// weights scattered into a 16x32 band matrix W (LDS), O^T = V_band^T @ W^T
// via MFMA (4).  No 64-lane reductions anywhere.
// ---------------------------------------------------------------------------
__global__ __launch_bounds__(256) void deform_attn_band(
    const u16* __restrict__ q, const u16* __restrict__ k,
    const u16* __restrict__ v, const float* __restrict__ offlog,
    u16* __restrict__ out, int B, int L)
{
    __shared__ u16  sVt[4][64 * 40];   // per-wave V-band transposed [d][c], pad 40
    __shared__ float sS[4][16 * 36];   // per-wave S band scores [l][c], pad 36
    __shared__ float sW[4][16 * 36];   // per-wave band weights  [l][c], pad 36

    const int wave = threadIdx.x >> 6;
    const int lane = threadIdx.x & 63;
    const int gw = blockIdx.x * 4 + wave;     // over B*NH*(L/16)
    const int nlb = L >> 4;
    const int lblk = gw % nlb;
    const int bh = gw / nlb;
    const int h = bh % NH;
    const int b = bh / NH;
    const int l0 = lblk << 4;

    u16*  __restrict__ vt = sVt[wave];
    float* __restrict__ Ss = sS[wave];
    float* __restrict__ Ws = sW[wave];

    const size_t brow = (size_t)b * L;
    const int headoff = h * DD;

    // ---- early: offsets/logits for this lane's (l,p) ----
    const int l_loc = lane >> 2, p = lane & 3;
    const size_t obase = (brow + l0 + l_loc) * 64 + h * 4 + p;
    const float offv  = offlog[obase];
    const float logit = offlog[obase + 32];

    const int fr = lane & 15, kg = lane >> 4;

    // ---- q A-frags (rows l0+fr, k = d) ----
    const u16* qrow = q + (brow + l0 + fr) * DM + headoff;
    frag_ab qf0 = *(const frag_ab*)(qrow + kg * 8);
    frag_ab qf1 = *(const frag_ab*)(qrow + kg * 8 + 32);

    // ---- K band B-frags (n = band col c, k = d) ----
    frag_ab kf[2][2];
#pragma unroll
    for (int jf = 0; jf < 2; ++jf) {
        int rr = l0 - 8 + jf * 16 + fr;
        rr = min(max(rr, 0), L - 1);
        const u16* krow = k + (brow + rr) * DM + headoff;
        kf[jf][0] = *(const frag_ab*)(krow + kg * 8);
        kf[jf][1] = *(const frag_ab*)(krow + kg * 8 + 32);
    }

    // ---- V band rows -> registers (for LDS transpose) ----
    const int vr = lane & 31, vd0 = (lane >> 5) * 32;
    int vrr = min(max(l0 - 8 + vr, 0), L - 1);
    const u16* vrow = v + (brow + vrr) * DM + headoff + vd0;
    frag_ab vl[4];
#pragma unroll
    for (int i = 0; i < 4; ++i)
        vl[i] = *(const frag_ab*)(vrow + i * 8);

    // ---- S = q @ k_band^T : C[l][c], 16x32 ----
    f32x4 accS[2] = {};
#pragma unroll
    for (int jf = 0; jf < 2; ++jf) {
        accS[jf] = __builtin_amdgcn_mfma_f32_16x16x32_bf16(qf0, kf[jf][0], accS[jf], 0, 0, 0);
        accS[jf] = __builtin_amdgcn_mfma_f32_16x16x32_bf16(qf1, kf[jf][1], accS[jf], 0, 0, 0);
    }

    // ---- transpose V into LDS: vt[d][c] ----
#pragma unroll
    for (int i = 0; i < 4; ++i)
#pragma unroll
        for (int j = 0; j < 8; ++j)
            vt[(vd0 + i * 8 + j) * 40 + vr] = (u16)vl[i][j];

    // ---- S frags -> LDS ----
#pragma unroll
    for (int jf = 0; jf < 2; ++jf)
#pragma unroll
        for (int r = 0; r < 4; ++r)
            Ss[(kg * 4 + r) * 36 + jf * 16 + fr] = accS[jf][r];

    // ---- zero band-weight matrix ----
#pragma unroll
    for (int i = 0; i < 9; ++i)
        Ws[lane + 64 * i] = 0.f;

    __syncthreads();

    // ---- softmax + interp weights: lane = (l_loc, p) ----
    float pos = fminf(fmaxf((float)(l0 + l_loc) + offv, 0.f), (float)(L - 1));
    float ff = floorf(pos);
    int i0 = (int)ff;
    float fw = pos - ff;
    int c0 = i0 - (l0 - 8);
    c0 = min(max(c0, 0), 30);            // safety clamp (band is 12+ sigma wide)
    float S0 = Ss[l_loc * 36 + c0];
    float S1 = Ss[l_loc * 36 + c0 + 1];
    float t = (S0 + fw * (S1 - S0)) * 0.125f + logit;
    float m1 = fmaxf(t, __shfl_xor(t, 1));
    float mx = fmaxf(m1, __shfl_xor(m1, 2));
    float e = __expf(t - mx);
    float s1 = e + __shfl_xor(e, 1);
    float ssum = s1 + __shfl_xor(s1, 2);
    float wgt = e * __builtin_amdgcn_rcpf(ssum);
    atomicAdd(&Ws[l_loc * 36 + c0], (1.f - fw) * wgt);
    atomicAdd(&Ws[l_loc * 36 + c0 + 1], fw * wgt);

    __syncthreads();

    // ---- W B-frag: lane n=fr (=l), k = c = kg*8+j ----
    float4 w0 = *(const float4*)&Ws[fr * 36 + kg * 8];
    float4 w1 = *(const float4*)&Ws[fr * 36 + kg * 8 + 4];
    frag_ab wf;
    wf[0] = (short)f2b(w0.x); wf[1] = (short)f2b(w0.y);
    wf[2] = (short)f2b(w0.z); wf[3] = (short)f2b(w0.w);
    wf[4] = (short)f2b(w1.x); wf[5] = (short)f2b(w1.y);
    wf[6] = (short)f2b(w1.z); wf[7] = (short)f2b(w1.w);

    // ---- O^T[d][l] = V_band^T @ W^T : 4 m-frags over d ----
#pragma unroll
    for (int md = 0; md < 4; ++md) {
        frag_ab af = *(const frag_ab*)&vt[(md * 16 + fr) * 40 + kg * 8];
        f32x4 o = {};
        o = __builtin_amdgcn_mfma_f32_16x16x32_bf16(af, wf, o, 0, 0, 0);
        // C: col = fr = l_loc, rows = d = md*16 + kg*4 + r
        ushort4 pk;
        pk.x = f2b(o[0]); pk.y = f2b(o[1]); pk.z = f2b(o[2]); pk.w = f2b(o[3]);
        *(ushort4*)&out[(brow + l0 + fr) * DM + headoff + md * 16 + kg * 4] = pk;
    }
}

// ---------------------------------------------------------------------------
extern "C" void kernel_launch(void* const* d_in, const int* in_sizes, int n_in,
                              void* d_out, int out_size, void* d_ws, size_t ws_size,
                              hipStream_t stream) {
    const float* q_in  = (const float*)d_in[0];
    const float* kv_in = (const float*)d_in[1];
    const float* Wq = (const float*)d_in[2];  const float* bq = (const float*)d_in[3];
    const float* Wk = (const float*)d_in[4];  const float* bk = (const float*)d_in[5];
    const float* Wv = (const float*)d_in[6];  const float* bv = (const float*)d_in[7];
    const float* Woff=(const float*)d_in[8];  const float* boff=(const float*)d_in[9];
    const float* Wa = (const float*)d_in[10]; const float* ba = (const float*)d_in[11];
    const float* Wo = (const float*)d_in[12]; const float* bo = (const float*)d_in[13];

    const int M = in_sizes[0] / DM;     // B*L = 16384
    const int L = 4096;
    const int B = M / L;

    char* p = (char*)d_ws;
    u16* qb    = (u16*)p;                 p += (size_t)M * DM * 2;     // attn out later
    u16* kvb   = (u16*)p;                 p += (size_t)M * DM * 2;
    u16* Wqb   = (u16*)p;                 p += (size_t)DM * DM * 2;
    u16* Wkb   = (u16*)p;                 p += (size_t)DM * DM * 2;
    u16* Wvb   = (u16*)p;                 p += (size_t)DM * DM * 2;
    u16* Wob   = (u16*)p;                 p += (size_t)DM * DM * 2;
    u16* wcomb = (u16*)p;                 p += (size_t)64 * DM * 2;
    float* bc  = (float*)p;               p += 64 * 4;
    u16* q_ws  = (u16*)p;                 p += (size_t)M * DM * 2;
    u16* k_ws  = (u16*)p;                 p += (size_t)M * DM * 2;
    u16* v_ws  = (u16*)p;                 p += (size_t)M * DM * 2;
    float* offlog = (float*)p;            p += (size_t)M * 64 * 4;

    dim3 blk(256);

    int n4 = (M * DM) / 4;
    hipLaunchKernelGGL(cast_f32_to_bf16, dim3((n4 + 255) / 256), blk, 0, stream, q_in,  qb,  n4);
    hipLaunchKernelGGL(cast_f32_to_bf16, dim3((n4 + 255) / 256), blk, 0, stream, kv_in, kvb, n4);
    int per4 = (DM * DM) / 4;
    hipLaunchKernelGGL(cast_weights4, dim3((4 * per4) / 256), blk, 0, stream,
                       Wq, Wk, Wv, Wo, Wqb, Wkb, Wvb, Wob, per4);
    hipLaunchKernelGGL(pack_offa, dim3((32 * DM + 255) / 256), blk, 0, stream,
                       Woff, Wa, boff, ba, wcomb, bc, 32 * DM);

    dim3 g512(M / 128, DM / 128);
    hipLaunchKernelGGL((gemm_bt_bf16<128, true>), g512, blk, 0, stream, qb,  Wqb, bq, q_ws, M, DM, DM);
    hipLaunchKernelGGL((gemm_bt_bf16<128, true>), g512, blk, 0, stream, kvb, Wkb, bk, k_ws, M, DM, DM);
    hipLaunchKernelGGL((gemm_bt_bf16<128, true>), g512, blk, 0, stream, kvb, Wvb, bv, v_ws, M, DM, DM);
    hipLaunchKernelGGL((gemm_bt_bf16<64, false>), dim3(M / 128, 1), blk, 0, stream,
                       qb, wcomb, bc, offlog, M, 64, DM);

    // banded attention: 1 wave per (b,h,16 queries)
    int nwaves = B * NH * (L / 16);
    hipLaunchKernelGGL(deform_attn_band, dim3(nwaves / 4), blk, 0, stream,
                       q_ws, k_ws, v_ws, offlog, qb, B, L);

    hipLaunchKernelGGL((gemm_bt_bf16<128, false>), g512, blk, 0, stream,
                       qb, Wob, bo, (float*)d_out, M, DM, DM);
}

// Round 4
// 223.743 us; speedup vs baseline: 3.3484x; 1.0569x over previous
//
#include <hip/hip_runtime.h>
#include <math.h>

#define NH 8
#define NP 4
#define DD 64
#define DM 512

typedef unsigned short u16;
typedef unsigned int u32;

using frag_ab = __attribute__((ext_vector_type(8))) short;  // 8 bf16 (4 VGPRs)
using f32x4   = __attribute__((ext_vector_type(4))) float;  // 4 fp32 acc

__device__ __forceinline__ u16 f2b(float f) {               // fp32 -> bf16 (RNE)
    u32 u = __float_as_uint(f);
    u32 r = (u + 0x7FFFu + ((u >> 16) & 1u)) >> 16;
    return (u16)r;
}
__device__ __forceinline__ float b2f(u16 b) {
    return __uint_as_float(((u32)b) << 16);
}

#define GLOBAL_AS __attribute__((address_space(1)))
#define LDS_AS    __attribute__((address_space(3)))
__device__ __forceinline__ void async_copy16(void* lds, const void* g) {
    __builtin_amdgcn_global_load_lds((const GLOBAL_AS u32*)g, (LDS_AS u32*)lds, 16, 0, 0);
}

// ---------------------------------------------------------------------------
// C = A[M,K](bf16) @ Wt[N,K](bf16)^T + bias[N](f32).  BM=BN=128, BK=32.
// MODE 0: C0 = f32, ld=N.   MODE 1: C0 = bf16, ld=N.
// MODE 2: split at col 512: col<512 -> bf16 C0 (ld 512); col>=512 -> f32 C1
//         (ld 64, col-512); frags with colbase>=N skipped (tail tile).
// ---------------------------------------------------------------------------
template <int MODE>
__global__ __launch_bounds__(256) void gemm_bt_bf16(
    const u16* __restrict__ A, const u16* __restrict__ Wt,
    const float* __restrict__ bias, void* __restrict__ C0,
    void* __restrict__ C1, int M, int N, int K)
{
    constexpr int BM = 128, BK = 32;
    __shared__ u16 sA[BM * BK];
    __shared__ u16 sB[BM * BK];

    const int tid  = threadIdx.x;
    const int wave = tid >> 6;
    const int lane = tid & 63;
    const int m0 = blockIdx.x * BM;
    const int n0 = blockIdx.y * BM;

    const int wrow = 64 * (wave >> 1);
    const int wcol = 64 * (wave & 1);

    f32x4 acc[4][4] = {};

    const int lr = lane & 15;
    const int kg = lane >> 4;

    const int kiters = K >> 5;
    for (int kt = 0; kt < kiters; ++kt) {
        const int k0 = kt << 5;
#pragma unroll
        for (int i = 0; i < 2; ++i) {
            int grp = i * 4 + wave;
            int c   = grp * 64 + lane;
            const u16* g = A + (size_t)(m0 + (c >> 2)) * K + k0 + ((c & 3) << 3);
            async_copy16(&sA[grp * 512], g);
        }
#pragma unroll
        for (int i = 0; i < 2; ++i) {
            int grp = i * 4 + wave;
            int c   = grp * 64 + lane;
            const u16* g = Wt + (size_t)(n0 + (c >> 2)) * K + k0 + ((c & 3) << 3);
            async_copy16(&sB[grp * 512], g);
        }
        __syncthreads();

        frag_ab af[4], bfr[4];
#pragma unroll
        for (int i = 0; i < 4; ++i)
            af[i] = *(const frag_ab*)&sA[(wrow + i * 16 + lr) * 32 + kg * 8];
#pragma unroll
        for (int j = 0; j < 4; ++j)
            bfr[j] = *(const frag_ab*)&sB[(wcol + j * 16 + lr) * 32 + kg * 8];
#pragma unroll
        for (int i = 0; i < 4; ++i)
#pragma unroll
            for (int j = 0; j < 4; ++j)
                acc[i][j] = __builtin_amdgcn_mfma_f32_16x16x32_bf16(
                    af[i], bfr[j], acc[i][j], 0, 0, 0);
        __syncthreads();
    }

    const int crow0 = (lane >> 4) * 4;
#pragma unroll
    for (int i = 0; i < 4; ++i) {
#pragma unroll
        for (int j = 0; j < 4; ++j) {
            const int colbase = n0 + wcol + j * 16;
            if (MODE == 2 && colbase >= N) continue;   // wave-uniform skip
            const int col = colbase + (lane & 15);
            float bv = bias[col];
#pragma unroll
            for (int r = 0; r < 4; ++r) {
                int row = m0 + wrow + i * 16 + crow0 + r;
                float val = acc[i][j][r] + bv;
                if (MODE == 0) {
                    ((float*)C0)[(size_t)row * N + col] = val;
                } else if (MODE == 1) {
                    ((u16*)C0)[(size_t)row * N + col] = f2b(val);
                } else {
                    if (colbase < 512)
                        ((u16*)C0)[(size_t)row * 512 + col] = f2b(val);
                    else
                        ((float*)C1)[(size_t)row * 64 + (col - 512)] = val;
                }
            }
        }
    }
}

// ---------------------------------------------------------------------------
// one-shot input cast: q_in, kv_in (fp32) -> qb, kvb (bf16), float4 granules
// ---------------------------------------------------------------------------
__global__ __launch_bounds__(256) void cast_inputs(
    const float* __restrict__ q_in, const float* __restrict__ kv_in,
    u16* __restrict__ qb, u16* __restrict__ kvb, int n4each)
{
    int i = blockIdx.x * 256 + threadIdx.x;
    const float* src; u16* dst; int off;
    if (i < n4each) { src = q_in; dst = qb; off = i; }
    else            { src = kv_in; dst = kvb; off = i - n4each; if (off >= n4each) return; }
    float4 v = ((const float4*)src)[off];
    ushort4 o;
    o.x = f2b(v.x); o.y = f2b(v.y); o.z = f2b(v.z); o.w = f2b(v.w);
    ((ushort4*)dst)[off] = o;
}

// ---------------------------------------------------------------------------
// pack all weights -> bf16 concatenated + bias concats (one launch)
//   Wcat1 = [Wq; Woff; Wa]  (576 x 512)   bcat1 = [bq; boff; ba] (576)
//   Wcat2 = [Wk; Wv]        (1024 x 512)  bcat2 = [bk; bv]       (1024)
//   Wob   = Wo              (512 x 512)
// ---------------------------------------------------------------------------
__global__ __launch_bounds__(256) void pack_weights(
    const float* __restrict__ Wq, const float* __restrict__ Woff,
    const float* __restrict__ Wa, const float* __restrict__ Wk,
    const float* __restrict__ Wv, const float* __restrict__ Wo,
    const float* __restrict__ bq, const float* __restrict__ boff,
    const float* __restrict__ ba, const float* __restrict__ bk,
    const float* __restrict__ bv, u16* __restrict__ Wcat1,
    u16* __restrict__ Wcat2, u16* __restrict__ Wob,
    float* __restrict__ bcat1, float* __restrict__ bcat2)
{
    const int W4  = 65536;   // 512*512/4
    const int W4s = 4096;    // 32*512/4
    int tid = blockIdx.x * 256 + threadIdx.x;
    if (tid < 3 * W4 + 2 * W4s) {
        const float* src; u16* dst; int off;
        if (tid < W4)                 { src = Wq;   dst = Wcat1;               off = tid; }
        else if (tid < W4 + W4s)      { src = Woff; dst = Wcat1 + 262144;      off = tid - W4; }
        else if (tid < W4 + 2 * W4s)  { src = Wa;   dst = Wcat1 + 278528;      off = tid - W4 - W4s; }
        else if (tid < 2 * W4 + 2*W4s){ src = Wk;   dst = Wcat2;               off = tid - W4 - 2 * W4s; }
        else                          { src = Wv;   dst = Wcat2 + 262144;      off = tid - 2 * W4 - 2 * W4s; }
        float4 v = ((const float4*)src)[off];
        ushort4 o;
        o.x = f2b(v.x); o.y = f2b(v.y); o.z = f2b(v.z); o.w = f2b(v.w);
        ((ushort4*)dst)[off] = o;
    } else if (tid < 4 * W4 + 2 * W4s) {
        int off = tid - 3 * W4 - 2 * W4s;
        float4 v = ((const float4*)Wo)[off];
        ushort4 o;
        o.x = f2b(v.x); o.y = f2b(v.y); o.z = f2b(v.z); o.w = f2b(v.w);
        ((ushort4*)Wob)[off] = o;
    } else {
        int j = tid - 4 * W4 - 2 * W4s;
        if (j < 576) {
            bcat1[j] = (j < 512) ? bq[j] : (j < 544 ? boff[j - 512] : ba[j - 544]);
        } else if (j < 1600) {
            int j2 = j - 576;
            bcat2[j2] = (j2 < 512) ? bk[j2] : bv[j2 - 512];
        }
    }
}

// ---------------------------------------------------------------------------
// Banded deformable attention. One wave per (b, h, 16-query block).
// k|v fused buffer: row stride 1024, k at col 0..511, v at col 512..1023.
// ---------------------------------------------------------------------------
__global__ __launch_bounds__(256) void deform_attn_band(
    const u16* __restrict__ q, const u16* __restrict__ kv,
    const float* __restrict__ offlog, u16* __restrict__ out, int B, int L)
{
    __shared__ u16  sVt[4][64 * 40];
    __shared__ float sS[4][16 * 36];
    __shared__ float sW[4][16 * 36];

    const int wave = threadIdx.x >> 6;
    const int lane = threadIdx.x & 63;
    const int gw = blockIdx.x * 4 + wave;     // over B*NH*(L/16)
    const int nlb = L >> 4;
    const int lblk = gw % nlb;
    const int bh = gw / nlb;
    const int h = bh % NH;
    const int b = bh / NH;
    const int l0 = lblk << 4;

    u16*  __restrict__ vt = sVt[wave];
    float* __restrict__ Ss = sS[wave];
    float* __restrict__ Ws = sW[wave];

    const size_t brow = (size_t)b * L;
    const int headoff = h * DD;

    const int l_loc = lane >> 2, p = lane & 3;
    const size_t obase = (brow + l0 + l_loc) * 64 + h * 4 + p;
    const float offv  = offlog[obase];
    const float logit = offlog[obase + 32];

    const int fr = lane & 15, kg = lane >> 4;

    // q A-frags (rows l0+fr, k = d); q stride 512
    const u16* qrow = q + (brow + l0 + fr) * DM + headoff;
    frag_ab qf0 = *(const frag_ab*)(qrow + kg * 8);
    frag_ab qf1 = *(const frag_ab*)(qrow + kg * 8 + 32);

    // K band B-frags; kv stride 1024
    frag_ab kf[2][2];
#pragma unroll
    for (int jf = 0; jf < 2; ++jf) {
        int rr = l0 - 8 + jf * 16 + fr;
        rr = min(max(rr, 0), L - 1);
        const u16* krow = kv + (brow + rr) * 1024 + headoff;
        kf[jf][0] = *(const frag_ab*)(krow + kg * 8);
        kf[jf][1] = *(const frag_ab*)(krow + kg * 8 + 32);
    }

    // V band rows -> registers
    const int vr = lane & 31, vd0 = (lane >> 5) * 32;
    int vrr = min(max(l0 - 8 + vr, 0), L - 1);
    const u16* vrow = kv + (brow + vrr) * 1024 + 512 + headoff + vd0;
    frag_ab vl[4];
#pragma unroll
    for (int i = 0; i < 4; ++i)
        vl[i] = *(const frag_ab*)(vrow + i * 8);

    // S = q @ k_band^T
    f32x4 accS[2] = {};
#pragma unroll
    for (int jf = 0; jf < 2; ++jf) {
        accS[jf] = __builtin_amdgcn_mfma_f32_16x16x32_bf16(qf0, kf[jf][0], accS[jf], 0, 0, 0);
        accS[jf] = __builtin_amdgcn_mfma_f32_16x16x32_bf16(qf1, kf[jf][1], accS[jf], 0, 0, 0);
    }

    // transpose V into LDS: vt[d][c]
#pragma unroll
    for (int i = 0; i < 4; ++i)
#pragma unroll
        for (int j = 0; j < 8; ++j)
            vt[(vd0 + i * 8 + j) * 40 + vr] = (u16)vl[i][j];

    // S frags -> LDS
#pragma unroll
    for (int jf = 0; jf < 2; ++jf)
#pragma unroll
        for (int r = 0; r < 4; ++r)
            Ss[(kg * 4 + r) * 36 + jf * 16 + fr] = accS[jf][r];

#pragma unroll
    for (int i = 0; i < 9; ++i)
        Ws[lane + 64 * i] = 0.f;

    __syncthreads();

    // softmax + interp weights; lane = (l_loc, p)
    float pos = fminf(fmaxf((float)(l0 + l_loc) + offv, 0.f), (float)(L - 1));
    float ff = floorf(pos);
    int i0 = (int)ff;
    float fw = pos - ff;
    int c0 = i0 - (l0 - 8);
    c0 = min(max(c0, 0), 30);
    float S0 = Ss[l_loc * 36 + c0];
    float S1 = Ss[l_loc * 36 + c0 + 1];
    float t = (S0 + fw * (S1 - S0)) * 0.125f + logit;
    float m1 = fmaxf(t, __shfl_xor(t, 1));
    float mx = fmaxf(m1, __shfl_xor(m1, 2));
    float e = __expf(t - mx);
    float s1 = e + __shfl_xor(e, 1);
    float ssum = s1 + __shfl_xor(s1, 2);
    float wgt = e * __builtin_amdgcn_rcpf(ssum);
    atomicAdd(&Ws[l_loc * 36 + c0], (1.f - fw) * wgt);
    atomicAdd(&Ws[l_loc * 36 + c0 + 1], fw * wgt);

    __syncthreads();

    float4 w0 = *(const float4*)&Ws[fr * 36 + kg * 8];
    float4 w1 = *(const float4*)&Ws[fr * 36 + kg * 8 + 4];
    frag_ab wf;
    wf[0] = (short)f2b(w0.x); wf[1] = (short)f2b(w0.y);
    wf[2] = (short)f2b(w0.z); wf[3] = (short)f2b(w0.w);
    wf[4] = (short)f2b(w1.x); wf[5] = (short)f2b(w1.y);
    wf[6] = (short)f2b(w1.z); wf[7] = (short)f2b(w1.w);

#pragma unroll
    for (int md = 0; md < 4; ++md) {
        frag_ab af = *(const frag_ab*)&vt[(md * 16 + fr) * 40 + kg * 8];
        f32x4 o = {};
        o = __builtin_amdgcn_mfma_f32_16x16x32_bf16(af, wf, o, 0, 0, 0);
        ushort4 pk;
        pk.x = f2b(o[0]); pk.y = f2b(o[1]); pk.z = f2b(o[2]); pk.w = f2b(o[3]);
        *(ushort4*)&out[(brow + l0 + fr) * DM + headoff + md * 16 + kg * 4] = pk;
    }
}

// ---------------------------------------------------------------------------
extern "C" void kernel_launch(void* const* d_in, const int* in_sizes, int n_in,
                              void* d_out, int out_size, void* d_ws, size_t ws_size,
                              hipStream_t stream) {
    const float* q_in  = (const float*)d_in[0];
    const float* kv_in = (const float*)d_in[1];
    const float* Wq = (const float*)d_in[2];  const float* bq = (const float*)d_in[3];
    const float* Wk = (const float*)d_in[4];  const float* bk = (const float*)d_in[5];
    const float* Wv = (const float*)d_in[6];  const float* bv = (const float*)d_in[7];
    const float* Woff=(const float*)d_in[8];  const float* boff=(const float*)d_in[9];
    const float* Wa = (const float*)d_in[10]; const float* ba = (const float*)d_in[11];
    const float* Wo = (const float*)d_in[12]; const float* bo = (const float*)d_in[13];

    const int M = in_sizes[0] / DM;     // B*L = 16384
    const int L = 4096;
    const int B = M / L;

    char* p = (char*)d_ws;
    u16* qb     = (u16*)p;               p += (size_t)M * DM * 2;     // attn out later
    u16* kvb    = (u16*)p;               p += (size_t)M * DM * 2;
    u16* Wcat1  = (u16*)p;               p += (size_t)640 * DM * 2;   // 576 used, 640 alloc
    u16* Wcat2  = (u16*)p;               p += (size_t)1024 * DM * 2;
    u16* Wob    = (u16*)p;               p += (size_t)DM * DM * 2;
    float* bcat1= (float*)p;             p += 640 * 4;
    float* bcat2= (float*)p;             p += 1024 * 4;
    u16* q_ws   = (u16*)p;               p += (size_t)M * DM * 2;
    u16* kv_ws  = (u16*)p;               p += (size_t)M * 1024 * 2;   // k|v fused
    float* offlog = (float*)p;           p += (size_t)M * 64 * 4;

    dim3 blk(256);

    int n4 = (M * DM) / 4;
    hipLaunchKernelGGL(cast_inputs, dim3((2 * n4 + 255) / 256), blk, 0, stream,
                       q_in, kv_in, qb, kvb, n4);
    hipLaunchKernelGGL(pack_weights, dim3((4 * 65536 + 2 * 4096 + 1600 + 255) / 256),
                       blk, 0, stream, Wq, Woff, Wa, Wk, Wv, Wo,
                       bq, boff, ba, bk, bv, Wcat1, Wcat2, Wob, bcat1, bcat2);

    // fused projections
    hipLaunchKernelGGL((gemm_bt_bf16<2>), dim3(M / 128, 5), blk, 0, stream,
                       qb, Wcat1, bcat1, q_ws, offlog, M, 576, DM);
    hipLaunchKernelGGL((gemm_bt_bf16<1>), dim3(M / 128, 8), blk, 0, stream,
                       kvb, Wcat2, bcat2, kv_ws, nullptr, M, 1024, DM);

    // banded attention: 1 wave per (b,h,16 queries); out -> qb
    int nwaves = B * NH * (L / 16);
    hipLaunchKernelGGL(deform_attn_band, dim3(nwaves / 4), blk, 0, stream,
                       q_ws, kv_ws, offlog, qb, B, L);

    // output projection -> fp32 d_out
    hipLaunchKernelGGL((gemm_bt_bf16<0>), dim3(M / 128, 4), blk, 0, stream,
                       qb, Wob, bo, (float*)d_out, nullptr, M, DM, DM);
}